// Round 11
// baseline (199.331 us; speedup 1.0000x reference)
//
#include <hip/hip_runtime.h>
#include <math.h>

// Single-head causal attention, B=8 T=2048 E=1024 D=64, fp32 in/out.
// wtrans (W -> bf16 W^T) -> qkv (BARRIER-FREE 4-wave blocks: waves share
// 16 tokens via L1, each owns one 16-feature slice of Q,K,V) -> attn
// (split-K + strip pairing + K register prefetch; unchanged from R10).

#define B_   8
#define T_   2048
#define E_   1024
#define D_   64
#define BT_  (B_ * T_)

typedef __attribute__((ext_vector_type(8))) short s16x8;   // 8 x bf16
typedef __attribute__((ext_vector_type(4))) short s16x4;
typedef __attribute__((ext_vector_type(4))) float f32x4;

__device__ __forceinline__ short f2bf(float f) {
    union { float f; unsigned u; } a; a.f = f;
    unsigned r = a.u + 0x7fffu + ((a.u >> 16) & 1u);   // RNE
    return (short)(r >> 16);
}

#define MFMA16(a, b, c) __builtin_amdgcn_mfma_f32_16x16x32_bf16((a), (b), (c), 0, 0, 0)

// DPP cross-lane move within 16-lane rows (VALU pipe, not DS).
#define DPPF(x, ctrl) __builtin_bit_cast(float, \
    __builtin_amdgcn_update_dpp(0, __builtin_bit_cast(int, (x)), (ctrl), 0xF, 0xF, true))

__device__ __forceinline__ float rsum16(float x) {
    x += DPPF(x, 0xB1);     // quad_perm xor1
    x += DPPF(x, 0x4E);     // quad_perm xor2
    x += DPPF(x, 0x124);    // row_ror:4
    x += DPPF(x, 0x128);    // row_ror:8
    return x;
}

// ---------------------------------------------------------------------------
// Kernel 0: W[1024][64] x3 (fp32) -> Wt[192][1024] (bf16, K-major).
// ---------------------------------------------------------------------------
__global__ __launch_bounds__(256) void wtrans_kernel(
    const float* __restrict__ Wq, const float* __restrict__ Wk,
    const float* __restrict__ Wv, short* __restrict__ Wt)
{
    __shared__ float sT[64][65];
    const int sel = blockIdx.x >> 4;            // 0=q 1=k 2=v
    const int k0  = (blockIdx.x & 15) * 64;
    const float* W = sel == 0 ? Wq : (sel == 1 ? Wk : Wv);
    const int t  = threadIdx.x;
    const int kr = t >> 4, c4 = (t & 15) * 4;
    #pragma unroll
    for (int i = 0; i < 4; ++i) {
        float4 v = *(const float4*)&W[(size_t)(k0 + kr + i * 16) * D_ + c4];
        sT[kr + i * 16][c4 + 0] = v.x; sT[kr + i * 16][c4 + 1] = v.y;
        sT[kr + i * 16][c4 + 2] = v.z; sT[kr + i * 16][c4 + 3] = v.w;
    }
    __syncthreads();
    #pragma unroll
    for (int i = 0; i < 4; ++i) {
        int n  = (t >> 4) + i * 16;
        int kk = (t & 15) * 4;
        s16x4 o;
        o.x = f2bf(sT[kk + 0][n]); o.y = f2bf(sT[kk + 1][n]);
        o.z = f2bf(sT[kk + 2][n]); o.w = f2bf(sT[kk + 3][n]);
        *(s16x4*)&Wt[(size_t)(sel * 64 + n) * E_ + k0 + kk] = o;
    }
}

// ---------------------------------------------------------------------------
// Kernel 1: QKV projection, barrier-free, 4 waves/block, grid 1024.
// All 4 waves use the SAME 16 tokens: their x loads are identical addresses
// -> L1 broadcasts (x chunk/iter = 4 KB, L1-resident). Wave w computes
// feature tiles {w, w+4, w+8} = 16-feature slices of Q, K, V. No
// __syncthreads anywhere -> no vmcnt(0) drain -> the 2-deep register x
// pipeline genuinely stays in flight; 4096 waves = 4/SIMD of TLP.
// ---------------------------------------------------------------------------
__global__ __launch_bounds__(256) void qkv_kernel(
    const float* __restrict__ x, const short* __restrict__ Wt,
    const float* __restrict__ bq, const float* __restrict__ bk,
    const float* __restrict__ bv,
    short* __restrict__ Qg, short* __restrict__ Kg, short* __restrict__ VTg)
{
    __shared__ short sVT[4][16 * 18];           // per-wave V-slice transpose
    const int tid  = threadIdx.x;
    const int lane = tid & 63;
    const int w    = tid >> 6;
    const int l15  = lane & 15, quad = lane >> 4;
    const int t0   = blockIdx.x * 16;
    const int bb   = t0 >> 11;                  // batch (16 | 2048)

    const float* px = &x[(size_t)(t0 + l15) * E_ + quad * 8];
    // wave w's three A rows: feature tiles w (Q), w+4 (K), w+8 (V)
    const short* pwA[3];
    #pragma unroll
    for (int t3 = 0; t3 < 3; ++t3)
        pwA[t3] = &Wt[(size_t)((w + 4 * t3) * 16 + l15) * E_ + quad * 8];

    f32x4 acc[3];
    #pragma unroll
    for (int t3 = 0; t3 < 3; ++t3) acc[t3] = (f32x4){0.f, 0.f, 0.f, 0.f};

    // x pipeline, 2 K-steps deep: 4 float4 per step (k0+quad*8, k0+32+quad*8)
    float4 xa[4], xb[4];
    xa[0] = *(const float4*)(px + 0);  xa[1] = *(const float4*)(px + 4);
    xa[2] = *(const float4*)(px + 32); xa[3] = *(const float4*)(px + 36);
    xb[0] = *(const float4*)(px + 64); xb[1] = *(const float4*)(px + 68);
    xb[2] = *(const float4*)(px + 96); xb[3] = *(const float4*)(px + 100);

    for (int k0 = 0; k0 < E_; k0 += 64) {
        s16x8 b0, b1;
        b0[0] = f2bf(xa[0].x); b0[1] = f2bf(xa[0].y);
        b0[2] = f2bf(xa[0].z); b0[3] = f2bf(xa[0].w);
        b0[4] = f2bf(xa[1].x); b0[5] = f2bf(xa[1].y);
        b0[6] = f2bf(xa[1].z); b0[7] = f2bf(xa[1].w);
        b1[0] = f2bf(xa[2].x); b1[1] = f2bf(xa[2].y);
        b1[2] = f2bf(xa[2].z); b1[3] = f2bf(xa[2].w);
        b1[4] = f2bf(xa[3].x); b1[5] = f2bf(xa[3].y);
        b1[6] = f2bf(xa[3].z); b1[7] = f2bf(xa[3].w);

        #pragma unroll
        for (int i = 0; i < 4; ++i) xa[i] = xb[i];   // shift pipeline
        if (k0 + 128 < E_) {                         // issue k0+128 loads
            const float* p2 = px + k0 + 128;
            xb[0] = *(const float4*)(p2 + 0);  xb[1] = *(const float4*)(p2 + 4);
            xb[2] = *(const float4*)(p2 + 32); xb[3] = *(const float4*)(p2 + 36);
        }

        // A-frags (L2-hot Wt); 6 independent loads, then 6 MFMAs
        s16x8 a0[3], a1[3];
        #pragma unroll
        for (int t3 = 0; t3 < 3; ++t3) {
            a0[t3] = *(const s16x8*)(pwA[t3] + k0);
            a1[t3] = *(const s16x8*)(pwA[t3] + k0 + 32);
        }
        #pragma unroll
        for (int t3 = 0; t3 < 3; ++t3) {
            acc[t3] = MFMA16(a0[t3], b0, acc[t3]);
            acc[t3] = MFMA16(a1[t3], b1, acc[t3]);
        }
    }

    // ---- epilogue. C: col(l15)=token, row(quad*4+r)=feature within tile.
    const int fb = w * 16 + quad * 4;           // feature base within D
    {   // Q (tile w): bias, 1/8 scale, packed 8B store
        f32x4 v = acc[0] + *(const f32x4*)&bq[fb];
        v *= 0.125f;
        s16x4 o = { f2bf(v[0]), f2bf(v[1]), f2bf(v[2]), f2bf(v[3]) };
        *(s16x4*)&Qg[(size_t)(t0 + l15) * D_ + fb] = o;
    }
    {   // K (tile w+4)
        f32x4 v = acc[1] + *(const f32x4*)&bk[fb];
        s16x4 o = { f2bf(v[0]), f2bf(v[1]), f2bf(v[2]), f2bf(v[3]) };
        *(s16x4*)&Kg[(size_t)(t0 + l15) * D_ + fb] = o;
    }
    {   // V (tile w+8): transpose via wave-private LDS (in-wave DS order)
        f32x4 v = acc[2] + *(const f32x4*)&bv[fb];
        #pragma unroll
        for (int r = 0; r < 4; ++r)
            sVT[w][(quad * 4 + r) * 18 + l15] = f2bf(v[r]);
        // lanes 0..31: feature f = lane>>1, half = lane&1 -> 16B store each
        if (lane < 32) {
            const int f = lane >> 1, half = lane & 1;
            s16x8 vv = *(const s16x8*)&sVT[w][f * 18 + half * 8];
            *(s16x8*)&VTg[(size_t)(bb * D_ + w * 16 + f) * T_
                          + (t0 & (T_ - 1)) + half * 8] = vv;
        }
    }
}

// ---------------------------------------------------------------------------
// Kernel 2: causal flash attention, split-K + strip pairing + next-chunk K
// register prefetch (R10, passing).
// ---------------------------------------------------------------------------
__global__ __launch_bounds__(256, 2) void attn_kernel(
    const short* __restrict__ Qg, const short* __restrict__ Kg,
    const short* __restrict__ VTg, float* __restrict__ out)
{
    __shared__ char smem[20736];
    short* sP = (short*)smem;                   // [4][16*72] bf16 (loop phase)
    float* sO = (float*)smem;                   // [4][64][20] fp32 (merge, union)
    float* sl = (float*)(smem + 20480);         // [4][16]

    const int tid  = threadIdx.x;
    const int lane = tid & 63;
    const int w    = tid >> 6;
    const int l15  = lane & 15, quad = lane >> 4;
    const int b    = blockIdx.x & 7;
    const int pr   = blockIdx.x >> 3;           // 0..63
    const int jA   = pr, jB = 127 - pr;
    const int tqA  = jA * 16, tqB = jB * 16;
    const int nchA = (jA >> 2) + 1, nchB = (jB >> 2) + 1;
    const int tot  = nchA + nchB;               // 32 or 33
    const int seg  = (tot + 3) >> 2;
    const int c0   = w * seg;
    const int c1   = (c0 + seg < tot) ? c0 + seg : tot;

    const size_t qoffA = ((size_t)b * T_ + tqA + l15) * D_ + quad * 8;
    const s16x8 aqA0 = *(const s16x8*)&Qg[qoffA];      // pre-scaled by 1/8
    const s16x8 aqA1 = *(const s16x8*)&Qg[qoffA + 32];
    const size_t qoffB = ((size_t)b * T_ + tqB + l15) * D_ + quad * 8;
    const s16x8 aqB0 = *(const s16x8*)&Qg[qoffB];
    const s16x8 aqB1 = *(const s16x8*)&Qg[qoffB + 32];

    f32x4 oA[4], oB[4];
    float lA[4] = {0.f, 0.f, 0.f, 0.f}, lB[4] = {0.f, 0.f, 0.f, 0.f};
    #pragma unroll
    for (int nt = 0; nt < 4; ++nt) {
        oA[nt] = (f32x4){0.f, 0.f, 0.f, 0.f};
        oB[nt] = (f32x4){0.f, 0.f, 0.f, 0.f};
    }

    const short* kb = Kg  + (size_t)b * T_ * D_;
    const short* vb = VTg + (size_t)b * D_ * T_;
    short* sPw = sP + w * (16 * 72);

    auto s0_of = [&](int c) {
        return (c < nchA) ? c * 64 : (c - nchA) * 64;
    };

    s16x8 kc[4][2];
    {
        const int s0 = s0_of(c0);
        #pragma unroll
        for (int nt = 0; nt < 4; ++nt) {
            const short* pk = kb + (size_t)(s0 + nt * 16 + l15) * D_ + quad * 8;
            kc[nt][0] = *(const s16x8*)pk;
            kc[nt][1] = *(const s16x8*)(pk + 32);
        }
    }

    for (int c = c0; c < c1; ++c) {
        const bool isA = (c < nchA);
        const int cc   = isA ? c : c - nchA;
        const int tq   = isA ? tqA : tqB;
        const int nch  = isA ? nchA : nchB;
        const int s0   = cc * 64;

        s16x8 nk[4][2];
        {
            const int sn = s0_of(c + 1 < c1 ? c + 1 : c);
            #pragma unroll
            for (int nt = 0; nt < 4; ++nt) {
                const short* pk = kb + (size_t)(sn + nt * 16 + l15) * D_ + quad * 8;
                nk[nt][0] = *(const s16x8*)pk;
                nk[nt][1] = *(const s16x8*)(pk + 32);
            }
        }

        const s16x8 q0 = isA ? aqA0 : aqB0;
        const s16x8 q1 = isA ? aqA1 : aqB1;
        const f32x4 zz = (f32x4){0.f, 0.f, 0.f, 0.f};
        f32x4 sacc[4];
        #pragma unroll
        for (int nt = 0; nt < 4; ++nt) {
            sacc[nt] = MFMA16(q0, kc[nt][0], zz);
            sacc[nt] = MFMA16(q1, kc[nt][1], sacc[nt]);
        }

        s16x8 bv[4][2];
        #pragma unroll
        for (int nt = 0; nt < 4; ++nt) {
            const short* pv = vb + (size_t)(nt * 16 + l15) * T_ + s0 + quad * 8;
            bv[nt][0] = *(const s16x8*)pv;
            bv[nt][1] = *(const s16x8*)(pv + 32);
        }

        const bool diag = (cc == nch - 1);
        float p[4][4];
        #pragma unroll
        for (int nt = 0; nt < 4; ++nt)
            #pragma unroll
            for (int r = 0; r < 4; ++r) {
                float e = __expf(sacc[nt][r]);
                if (diag && (s0 + nt * 16 + l15 > tq + quad * 4 + r)) e = 0.f;
                p[nt][r] = e;
            }

        #pragma unroll
        for (int nt = 0; nt < 4; ++nt)
            #pragma unroll
            for (int r = 0; r < 4; ++r)
                sPw[(quad * 4 + r) * 72 + nt * 16 + l15] = f2bf(p[nt][r]);
        s16x8 ap0 = *(const s16x8*)&sPw[l15 * 72 + quad * 8];
        s16x8 ap1 = *(const s16x8*)&sPw[l15 * 72 + 32 + quad * 8];

        if (isA) {
            #pragma unroll
            for (int r = 0; r < 4; ++r)
                lA[r] += (p[0][r] + p[1][r]) + (p[2][r] + p[3][r]);
            #pragma unroll
            for (int nt = 0; nt < 4; ++nt) {
                oA[nt] = MFMA16(ap0, bv[nt][0], oA[nt]);
                oA[nt] = MFMA16(ap1, bv[nt][1], oA[nt]);
            }
        } else {
            #pragma unroll
            for (int r = 0; r < 4; ++r)
                lB[r] += (p[0][r] + p[1][r]) + (p[2][r] + p[3][r]);
            #pragma unroll
            for (int nt = 0; nt < 4; ++nt) {
                oB[nt] = MFMA16(ap0, bv[nt][0], oB[nt]);
                oB[nt] = MFMA16(ap1, bv[nt][1], oB[nt]);
            }
        }

        #pragma unroll
        for (int nt = 0; nt < 4; ++nt) {
            kc[nt][0] = nk[nt][0]; kc[nt][1] = nk[nt][1];
        }
    }

    f32x4 lvA, lvB;
    #pragma unroll
    for (int r = 0; r < 4; ++r) { lvA[r] = rsum16(lA[r]); lvB[r] = rsum16(lB[r]); }

    const int d  = tid & 63;
    const int rb = (tid >> 6) * 4;

    // ---- merge strip A
    __syncthreads();                            // all waves done with sP
    {
        float* sOw = sO + w * (64 * 20);
        #pragma unroll
        for (int nt = 0; nt < 4; ++nt)
            *(f32x4*)&sOw[(nt * 16 + l15) * 20 + quad * 4] = oA[nt];
        if (l15 == 0) *(f32x4*)&sl[w * 16 + quad * 4] = lvA;
    }
    __syncthreads();
    {
        f32x4 osum = (f32x4){0.f, 0.f, 0.f, 0.f};
        f32x4 lsum = (f32x4){0.f, 0.f, 0.f, 0.f};
        #pragma unroll
        for (int w2 = 0; w2 < 4; ++w2) {
            osum += *(const f32x4*)&sO[w2 * (64 * 20) + d * 20 + rb];
            lsum += *(const f32x4*)&sl[w2 * 16 + rb];
        }
        #pragma unroll
        for (int i = 0; i < 4; ++i)
            out[((size_t)b * T_ + tqA + rb + i) * D_ + d] = osum[i] / lsum[i];
    }

    // ---- merge strip B
    __syncthreads();
    {
        float* sOw = sO + w * (64 * 20);
        #pragma unroll
        for (int nt = 0; nt < 4; ++nt)
            *(f32x4*)&sOw[(nt * 16 + l15) * 20 + quad * 4] = oB[nt];
        if (l15 == 0) *(f32x4*)&sl[w * 16 + quad * 4] = lvB;
    }
    __syncthreads();
    {
        f32x4 osum = (f32x4){0.f, 0.f, 0.f, 0.f};
        f32x4 lsum = (f32x4){0.f, 0.f, 0.f, 0.f};
        #pragma unroll
        for (int w2 = 0; w2 < 4; ++w2) {
            osum += *(const f32x4*)&sO[w2 * (64 * 20) + d * 20 + rb];
            lsum += *(const f32x4*)&sl[w2 * 16 + rb];
        }
        #pragma unroll
        for (int i = 0; i < 4; ++i)
            out[((size_t)b * T_ + tqB + rb + i) * D_ + d] = osum[i] / lsum[i];
    }
}

extern "C" void kernel_launch(void* const* d_in, const int* in_sizes, int n_in,
                              void* d_out, int out_size, void* d_ws, size_t ws_size,
                              hipStream_t stream) {
    (void)in_sizes; (void)n_in; (void)out_size; (void)ws_size;
    const float* x  = (const float*)d_in[0];
    const float* Wq = (const float*)d_in[1];
    const float* bq = (const float*)d_in[2];
    const float* Wk = (const float*)d_in[3];
    const float* bk = (const float*)d_in[4];
    const float* Wv = (const float*)d_in[5];
    const float* bv = (const float*)d_in[6];

    char* ws = (char*)d_ws;
    short* Qg  = (short*)(ws);                           // [BT][64] bf16, 2 MB
    short* Kg  = (short*)(ws + (size_t)2 * 1024 * 1024);
    short* VTg = (short*)(ws + (size_t)4 * 1024 * 1024); // [B][64][T] bf16
    short* Wt  = (short*)(ws + (size_t)6 * 1024 * 1024); // [192][1024] bf16

    wtrans_kernel<<<48, 256, 0, stream>>>(Wq, Wk, Wv, Wt);
    qkv_kernel<<<BT_ / 16, 256, 0, stream>>>(x, Wt, bq, bk, bv, Qg, Kg, VTg);
    attn_kernel<<<B_ * 64, 256, 0, stream>>>(Qg, Kg, VTg, (float*)d_out);
}